// Round 6
// baseline (221.312 us; speedup 1.0000x reference)
//
#include <hip/hip_runtime.h>

// out[s,a] = values[index[s,a]]
// index: 16384*2048 int32 (128 MiB), values: 100 fp32 (400 B), out: fp32 (128 MiB)
// Irreducible traffic: 268.4 MB -> ~42 us floor @ ~6.3-6.7 TB/s mixed-stream.
// R6: (a) per-wave LDS values copy -> NO __syncthreads (wave-lockstep + lgkmcnt
//     suffices; each wave reads only its own 400 B region);
//     (b) 2x int4 per thread, flat strided, loop-free; grid 4096 -> halves
//     wave count and prologue count. R4/R5 lesson: flat beats grid-stride.

constexpr int VOCAB = 100;

typedef int   vint4   __attribute__((ext_vector_type(4)));
typedef float vfloat4 __attribute__((ext_vector_type(4)));

__global__ __launch_bounds__(1024) void gather_kernel(
    const vint4* __restrict__ idx4,
    const float* __restrict__ vals,
    vfloat4* __restrict__ out4)
{
    // 16 waves/block, each with a private 100-float copy: no cross-wave
    // dependency -> no __syncthreads needed (compiler's lgkmcnt wait covers
    // the wave-local write->read ordering).
    __shared__ float svals[16][VOCAB];
    const int wave = threadIdx.x >> 6;
    const int lane = threadIdx.x & 63;
    float* sv = svals[wave];
    if (lane < VOCAB) sv[lane] = vals[lane];
    // lane 64..: VOCAB=100 > 64, second chunk
    if (lane + 64 < VOCAB) sv[lane + 64] = vals[lane + 64];

    const int S = gridDim.x * blockDim.x;                 // 4096*1024
    const int t = blockIdx.x * blockDim.x + threadIdx.x;  // flat, loop-free

    vint4 v0 = __builtin_nontemporal_load(&idx4[t]);
    vint4 v1 = __builtin_nontemporal_load(&idx4[t + S]);

    vfloat4 o0 = { sv[v0.x], sv[v0.y], sv[v0.z], sv[v0.w] };
    vfloat4 o1 = { sv[v1.x], sv[v1.y], sv[v1.z], sv[v1.w] };

    __builtin_nontemporal_store(o0, &out4[t]);
    __builtin_nontemporal_store(o1, &out4[t + S]);
}

extern "C" void kernel_launch(void* const* d_in, const int* in_sizes, int n_in,
                              void* d_out, int out_size, void* d_ws, size_t ws_size,
                              hipStream_t stream) {
    const int*   idx  = (const int*)d_in[0];     // 16384*2048 int32
    const float* vals = (const float*)d_in[1];   // 100 fp32
    float*       out  = (float*)d_out;           // fp32

    int n  = in_sizes[0];                        // 33554432
    int n4 = n / 4;                              // 8388608 = 2 * 4096 * 1024

    const int block = 1024;
    const int grid  = n4 / (2 * block);          // 4096 blocks, exact cover

    gather_kernel<<<grid, block, 0, stream>>>(
        (const vint4*)idx, vals, (vfloat4*)out);
}

// Round 7
// 218.783 us; speedup vs baseline: 1.0116x; 1.0116x over previous
//
#include <hip/hip_runtime.h>

// out[s,a] = values[index[s,a]]
// index: 16384*2048 int32 (128 MiB), values: 100 fp32 (400 B), out: fp32 (128 MiB)
// Irreducible traffic: 268.4 MB -> ~42 us floor @ ~6.3-6.7 TB/s mixed-stream.
// R7: disentangle R6 — revert to flat 1x int4/thread, block=1024, grid=8192
//     (R5 structure, best so far @217.25), keeping ONLY the per-wave LDS copy
//     without __syncthreads as the isolated variable.
// History: grid-stride 228 > flat2/thr 221.3 > flat256 218.8 > flat1024 217.25
//          -> max TLP, one access per thread is the winning structure.

constexpr int VOCAB = 100;

typedef int   vint4   __attribute__((ext_vector_type(4)));
typedef float vfloat4 __attribute__((ext_vector_type(4)));

__global__ __launch_bounds__(1024) void gather_kernel(
    const vint4* __restrict__ idx4,
    const float* __restrict__ vals,
    vfloat4* __restrict__ out4)
{
    // 16 waves/block, each fills its private 100-float copy: no cross-wave
    // dependency -> no __syncthreads (wave-lockstep + compiler lgkmcnt covers
    // the wave-local LDS write->read ordering).
    __shared__ float svals[16][VOCAB];
    const int wave = threadIdx.x >> 6;
    const int lane = threadIdx.x & 63;
    float* sv = svals[wave];
    if (lane < VOCAB) sv[lane] = vals[lane];
    if (lane + 64 < VOCAB) sv[lane + 64] = vals[lane + 64];

    const int t = blockIdx.x * blockDim.x + threadIdx.x;  // one int4 per thread

    vint4 v = __builtin_nontemporal_load(&idx4[t]);
    vfloat4 o = { sv[v.x], sv[v.y], sv[v.z], sv[v.w] };
    __builtin_nontemporal_store(o, &out4[t]);
}

extern "C" void kernel_launch(void* const* d_in, const int* in_sizes, int n_in,
                              void* d_out, int out_size, void* d_ws, size_t ws_size,
                              hipStream_t stream) {
    const int*   idx  = (const int*)d_in[0];     // 16384*2048 int32
    const float* vals = (const float*)d_in[1];   // 100 fp32
    float*       out  = (float*)d_out;           // fp32

    int n  = in_sizes[0];                        // 33554432
    int n4 = n / 4;                              // 8388608 = 8192 * 1024

    const int block = 1024;
    const int grid  = n4 / block;                // 8192 blocks, exact cover

    gather_kernel<<<grid, block, 0, stream>>>(
        (const vint4*)idx, vals, (vfloat4*)out);
}